// Round 9
// baseline (266.646 us; speedup 1.0000x reference)
//
#include <hip/hip_runtime.h>
#include <hip/hip_fp16.h>

#define HID 128
#define NGRAPH 64
#define CAP 64        // fixed CSR capacity per row (Poisson lambda=12 -> safe)
#define NPB 16        // nodes per block (4 waves x 4 nodes) -> 3125 blocks supply

typedef unsigned int uint32;
typedef unsigned short ushort;
using short8 = __attribute__((ext_vector_type(8))) short;
using f32x4  = __attribute__((ext_vector_type(4))) float;

// fp16 pack/unpack helpers (RNE via v_cvt)
__device__ __forceinline__ float2 h2f2(uint32 u) {
    __half2 h = *(__half2*)&u;
    return __half22float2(h);
}
__device__ __forceinline__ uint32 f2h2(float a, float b) {
    __half2 h;
    h.x = __float2half(a);
    h.y = __float2half(b);
    return *(uint32*)&h;
}

// unpack one fp16x8 row chunk and accumulate into 8 fp32 lane-cols
__device__ __forceinline__ void accum4(float* acc, uint4 v) {
    float2 e0 = h2f2(v.x), e1 = h2f2(v.y), e2 = h2f2(v.z), e3 = h2f2(v.w);
    acc[0] += e0.x; acc[1] += e0.y; acc[2] += e1.x; acc[3] += e1.y;
    acc[4] += e2.x; acc[5] += e2.y; acc[6] += e3.x; acc[7] += e3.y;
}

// ---------------------------------------------------------------------------
// setup: fill=0, zero fp16 pad row (row n) of BOTH gather planes (S1, S2),
// and build gstart[0..NGRAPH] segment-boundary table from sorted batch.
// ---------------------------------------------------------------------------
__global__ void setup(int* __restrict__ fill, uint32* __restrict__ s1,
                      uint32* __restrict__ s2, const int* __restrict__ batch,
                      int* __restrict__ gstart, int n) {
    int i = blockIdx.x * blockDim.x + threadIdx.x;
    if (i < n) fill[i] = 0;
    if (i < 64) {
        s1[(size_t)n * 64 + i] = 0u;     // zero pad row of layer-1 plane
        s2[(size_t)n * 64 + i] = 0u;     // zero pad row of layer-2 plane
    }
    if (i < n) {
        int b0 = batch[i];
        if (i == 0) {
            for (int g = 0; g <= b0; ++g) gstart[g] = 0;   // leading (possibly empty)
        }
        if (i + 1 < n) {
            int b1 = batch[i + 1];
            for (int g = b0 + 1; g <= b1; ++g) gstart[g] = i + 1;
        } else {
            for (int g = b0 + 1; g <= NGRAPH; ++g) gstart[g] = n;  // trailing
        }
    }
}

// ---------------------------------------------------------------------------
// capacity-CSR fill + weight pack fused (single atomic pass, no scan).
// blocks [0,EB): pos = fill[dst]++ ; csr[dst*CAP+pos] = src.
// blocks [EB,EB+128): pack W2,W3 -> transposed single-plane fp16 wt[sel][n][k].
// NOTE: int (not ushort) CSR deliberately — the ushort variant core-dumped
// on HW in a previous round.
// ---------------------------------------------------------------------------
__global__ void csr_fill_pack(const int* __restrict__ src, const int* __restrict__ dst,
                              int* __restrict__ fill, int* __restrict__ csr,
                              int E, int EB,
                              const float* __restrict__ W2, const float* __restrict__ W3,
                              ushort* __restrict__ wt) {
    int b = blockIdx.x;
    if (b < EB) {
        int e = b * blockDim.x + threadIdx.x;
        if (e >= E) return;
        int d = dst[e];
        int pos = atomicAdd(&fill[d], 1);
        if (pos < CAP) csr[(size_t)d * CAP + pos] = src[e];
    } else {
        int t = (b - EB) * blockDim.x + threadIdx.x;   // 0..32767
        int sel = t >> 14;                             // 0: W2, 1: W3
        int idx = t & 16383;
        int nn = idx >> 7, kk = idx & 127;
        const float* W = sel ? W3 : W2;
        wt[sel * 16384 + idx] = __half_as_ushort(__float2half(W[kk * HID + nn]));
    }
}

// ---------------------------------------------------------------------------
// finalize: dis = 1/sqrt(deg) with deg = fill+1 (self-loop); pack
// xp[i] = dis[i] * x[i,:] into 32 B rows (vector-gatherable by layer 1).
// ---------------------------------------------------------------------------
__global__ void finalize(const int* __restrict__ fill, float* __restrict__ dis,
                         const float* __restrict__ x, float4* __restrict__ xp4, int n) {
    int i = blockIdx.x * blockDim.x + threadIdx.x;
    if (i >= n) return;
    int d = fill[i] + 1;
    float di = (float)(1.0 / sqrt((double)d));
    dis[i] = di;
    const float* xi = x + (size_t)i * 6;
    xp4[(size_t)i * 2]     = make_float4(di * xi[0], di * xi[1], di * xi[2], di * xi[3]);
    xp4[(size_t)i * 2 + 1] = make_float4(di * xi[4], di * xi[5], 0.f, 0.f);
}

// ---------------------------------------------------------------------------
// fused layer 1: one wave per node; m <= 64 so each lane gathers its own
// edge's xp row directly, 6 butterfly reductions, then each lane emits
// 2 fp16 output cols.  Stores S1 = dis * relu(xa@W1+b1).
// ---------------------------------------------------------------------------
__global__ __launch_bounds__(256) void layer1_fused(
    const float4* __restrict__ xp4, const int* __restrict__ fill,
    const int* __restrict__ csr, const float* __restrict__ dis,
    const float* __restrict__ W1, const float* __restrict__ b1,
    uint32* __restrict__ S1, int n) {
    int t = blockIdx.x * blockDim.x + threadIdx.x;
    int i = t >> 6, lane = t & 63;
    if (i >= n) return;
    int m = fill[i]; if (m > CAP) m = CAP;
    float a0 = 0.f, a1 = 0.f, a2 = 0.f, a3 = 0.f, a4 = 0.f, a5 = 0.f;
    if (lane < m) {
        int s = csr[(size_t)i * CAP + lane];
        float4 p0 = xp4[(size_t)s * 2];
        float4 p1 = xp4[(size_t)s * 2 + 1];
        a0 = p0.x; a1 = p0.y; a2 = p0.z;
        a3 = p0.w; a4 = p1.x; a5 = p1.y;
    }
#pragma unroll
    for (int off = 32; off > 0; off >>= 1) {
        a0 += __shfl_xor(a0, off); a1 += __shfl_xor(a1, off);
        a2 += __shfl_xor(a2, off); a3 += __shfl_xor(a3, off);
        a4 += __shfl_xor(a4, off); a5 += __shfl_xor(a5, off);
    }
    float di = dis[i];
    float4 s0 = xp4[(size_t)i * 2];
    float4 s1 = xp4[(size_t)i * 2 + 1];
    float xa[6];
    xa[0] = di * (s0.x + a0); xa[1] = di * (s0.y + a1);
    xa[2] = di * (s0.z + a2); xa[3] = di * (s0.w + a3);
    xa[4] = di * (s1.x + a4); xa[5] = di * (s1.y + a5);
    int c0 = lane * 2;
    float z0 = b1[c0], z1 = b1[c0 + 1];
#pragma unroll
    for (int k = 0; k < 6; ++k) {
        z0 += xa[k] * W1[k * HID + c0];
        z1 += xa[k] * W1[k * HID + c0 + 1];
    }
    // scale by dis so the plane is directly gatherable as S = dis*h
    S1[(size_t)i * 64 + lane] = f2h2(di * fmaxf(z0, 0.f), di * fmaxf(z1, 0.f));
}

// ---------------------------------------------------------------------------
// FUSED GCN layer (layers 2 & 3): aggregate-then-GEMM.
//   P_i    = dis_i * (sum_{j in N(i)} Sin_j + Sin_i)     (wave CSR gather)
//   Sout_i = [dis_i *] relu(P_i @ W + b)                 (MFMA, 16x16x32 f16)
//
// R9: supply-side TLP. R8 counters showed the kernel is SUPPLY-limited
// (6.1 waves/SIMD from 1563 blocks; VGPR=60 would allow 8 resident).
// -> 16 nodes/block (4 waves x 4 nodes, 3125 blocks = 12.2 waves/SIMD
// supplied) with the simple proven 2-pair body (R1 inner loop, 8 uint4 in
// flight) and __launch_bounds__(256,8) pinning VGPR <= 64 so 8 waves/SIMD
// stay resident.  (R2's NPB=16 failed because its 16-deep pipeline compiled
// near 128 VGPR -> residency 4/SIMD; R8's cross-pair pipeline was sunk by
// the compiler to just-in-time issue, VGPR=60. Mechanism check this round:
// VGPR_Count == 64, layer dur ~37-41 us.)
// ---------------------------------------------------------------------------
template<int MINW>
__global__ __launch_bounds__(256, MINW) void layer_agg_gemm(
    const uint32* __restrict__ Sin, const int* __restrict__ fill,
    const int* __restrict__ csr, const float* __restrict__ dis,
    const ushort* __restrict__ WT, const float* __restrict__ bias,
    uint32* __restrict__ Sout, int n, int scaleOut) {
    __shared__ uint4 plds4[NPB * 17];           // 16 rows x 272 B = 4352 B
    const int wave = threadIdx.x >> 6;
    const int lane = threadIdx.x & 63;
    const int grp = lane >> 4;                  // edge-slot group 0..3
    const int q   = lane & 15;                  // uint4 col chunk (8 fp16)
    const int blk0 = blockIdx.x * NPB;
    const int base = blk0 + wave * 4;

    // ---- prologue: prefetch fill + csr index vectors for the 4 nodes ----
    int mt4[4];    // edge count incl. appended self-loop (<= 64)
    int idx4[4];   // this lane's edge slot for node j (pad -> zero row n)
#pragma unroll
    for (int j = 0; j < 4; ++j) {
        int i = base + j;
        int fv = (i < n) ? fill[i] : 0;
        int m = fv > CAP ? CAP : fv;
        idx4[j] = (lane < m) ? csr[(size_t)i * CAP + lane]
                             : ((lane == m && i < n && m < CAP) ? i : n);
        mt4[j] = m + (m < CAP ? 1 : 0);   // append self as slot m
    }

    // ---- phase A: paired gather-aggregate into LDS (2 pairs) ----
#pragma unroll
    for (int jp = 0; jp < 2; ++jp) {
        const int ja = jp * 2, jb = ja + 1;
        float acca[8] = {0.f, 0.f, 0.f, 0.f, 0.f, 0.f, 0.f, 0.f};
        float accb[8] = {0.f, 0.f, 0.f, 0.f, 0.f, 0.f, 0.f, 0.f};
        // first 16-edge round of BOTH nodes co-issued (8 uint4 in flight)
        {
            int sa1 = __shfl(idx4[ja], grp);
            int sa2 = __shfl(idx4[ja], 4 + grp);
            int sa3 = __shfl(idx4[ja], 8 + grp);
            int sa4 = __shfl(idx4[ja], 12 + grp);
            int sb1 = __shfl(idx4[jb], grp);
            int sb2 = __shfl(idx4[jb], 4 + grp);
            int sb3 = __shfl(idx4[jb], 8 + grp);
            int sb4 = __shfl(idx4[jb], 12 + grp);
            uint4 va1 = *(const uint4*)(Sin + (size_t)sa1 * 64 + q * 4);
            uint4 va2 = *(const uint4*)(Sin + (size_t)sa2 * 64 + q * 4);
            uint4 va3 = *(const uint4*)(Sin + (size_t)sa3 * 64 + q * 4);
            uint4 va4 = *(const uint4*)(Sin + (size_t)sa4 * 64 + q * 4);
            uint4 vb1 = *(const uint4*)(Sin + (size_t)sb1 * 64 + q * 4);
            uint4 vb2 = *(const uint4*)(Sin + (size_t)sb2 * 64 + q * 4);
            uint4 vb3 = *(const uint4*)(Sin + (size_t)sb3 * 64 + q * 4);
            uint4 vb4 = *(const uint4*)(Sin + (size_t)sb4 * 64 + q * 4);
            accum4(acca, va1); accum4(acca, va2);
            accum4(acca, va3); accum4(acca, va4);
            accum4(accb, vb1); accum4(accb, vb2);
            accum4(accb, vb3); accum4(accb, vb4);
        }
        // remainder rounds (m >= 16), serial per node
        for (int k = 16; k < mt4[ja]; k += 16) {
            int s1 = __shfl(idx4[ja], k + grp);
            int s2 = __shfl(idx4[ja], k + 4 + grp);
            int s3 = __shfl(idx4[ja], k + 8 + grp);
            int s4 = __shfl(idx4[ja], k + 12 + grp);
            uint4 v1 = *(const uint4*)(Sin + (size_t)s1 * 64 + q * 4);
            uint4 v2 = *(const uint4*)(Sin + (size_t)s2 * 64 + q * 4);
            uint4 v3 = *(const uint4*)(Sin + (size_t)s3 * 64 + q * 4);
            uint4 v4 = *(const uint4*)(Sin + (size_t)s4 * 64 + q * 4);
            accum4(acca, v1); accum4(acca, v2);
            accum4(acca, v3); accum4(acca, v4);
        }
        for (int k = 16; k < mt4[jb]; k += 16) {
            int s1 = __shfl(idx4[jb], k + grp);
            int s2 = __shfl(idx4[jb], k + 4 + grp);
            int s3 = __shfl(idx4[jb], k + 8 + grp);
            int s4 = __shfl(idx4[jb], k + 12 + grp);
            uint4 v1 = *(const uint4*)(Sin + (size_t)s1 * 64 + q * 4);
            uint4 v2 = *(const uint4*)(Sin + (size_t)s2 * 64 + q * 4);
            uint4 v3 = *(const uint4*)(Sin + (size_t)s3 * 64 + q * 4);
            uint4 v4 = *(const uint4*)(Sin + (size_t)s4 * 64 + q * 4);
            accum4(accb, v1); accum4(accb, v2);
            accum4(accb, v3); accum4(accb, v4);
        }
        // cross-group butterfly reduce (4 groups -> full row sums)
#pragma unroll
        for (int r = 0; r < 8; ++r) {
            acca[r] += __shfl_xor(acca[r], 16);
            acca[r] += __shfl_xor(acca[r], 32);
            accb[r] += __shfl_xor(accb[r], 16);
            accb[r] += __shfl_xor(accb[r], 32);
        }
        if (grp == 0) {
            int ia = base + ja, ib = base + jb;
            float da = (ia < n) ? dis[ia] : 0.f;
            float db = (ib < n) ? dis[ib] : 0.f;
            plds4[(wave * 4 + ja) * 17 + q] =
                make_uint4(f2h2(da * acca[0], da * acca[1]),
                           f2h2(da * acca[2], da * acca[3]),
                           f2h2(da * acca[4], da * acca[5]),
                           f2h2(da * acca[6], da * acca[7]));
            plds4[(wave * 4 + jb) * 17 + q] =
                make_uint4(f2h2(db * accb[0], db * accb[1]),
                           f2h2(db * accb[2], db * accb[3]),
                           f2h2(db * accb[4], db * accb[5]),
                           f2h2(db * accb[6], db * accb[7]));
        }
    }
    __syncthreads();

    // ---- phase B: 16x128 GEMM out = [dis*] relu(P @ W + b) ----
    // wave w owns cols [w*32, w*32+32); 16 rows; 8 MFMA per wave.
    const int l16 = lane & 15, quad = lane >> 4;
    f32x4 acc2[2] = {};
#pragma unroll
    for (int kc = 0; kc < 4; ++kc) {
        int ko = kc * 32 + quad * 8;
        short8 a0 = *(const short8*)&plds4[(size_t)l16 * 17 + kc * 4 + quad];
#pragma unroll
        for (int ct = 0; ct < 2; ++ct) {
            short8 wh = *(const short8*)(WT + (size_t)(wave * 32 + ct * 16 + l16) * HID + ko);
            acc2[ct] = __builtin_amdgcn_mfma_f32_16x16x32_f16(wh, a0, acc2[ct], 0, 0, 0);
        }
    }
    ushort* so = (ushort*)Sout;
    int node = blk0 + l16;
    if (node < n) {
        float sc = scaleOut ? dis[node] : 1.f;
#pragma unroll
        for (int ct = 0; ct < 2; ++ct) {
            int cb = wave * 32 + ct * 16 + quad * 4;
            float4 bv = *(const float4*)(bias + cb);
            float o0 = fmaxf(acc2[ct][0] + bv.x, 0.f) * sc;
            float o1 = fmaxf(acc2[ct][1] + bv.y, 0.f) * sc;
            float o2 = fmaxf(acc2[ct][2] + bv.z, 0.f) * sc;
            float o3 = fmaxf(acc2[ct][3] + bv.w, 0.f) * sc;
            *(uint2*)(so + (size_t)node * HID + cb) = make_uint2(f2h2(o0, o1), f2h2(o2, o3));
        }
    }
}

// ---------------------------------------------------------------------------
// FUSED pool + head: one block per graph; segment bounds from precomputed
// gstart table. 4 waves stream rows, LDS reduce, wave 0 runs the MLP head.
// ---------------------------------------------------------------------------
__global__ __launch_bounds__(256) void pool_head(
    const uint32* __restrict__ h, const int* __restrict__ gstart,
    const float* __restrict__ fc1w, const float* __restrict__ fc1b,
    const float* __restrict__ fc2w, const float* __restrict__ fc2b,
    float* __restrict__ out, int n) {
    __shared__ float red[4][128];
    __shared__ float pp[128];
    const int g = blockIdx.x;
    const int t = threadIdx.x;
    const int sub = t >> 6, c = t & 63;

    const int start = gstart[g], end = gstart[g + 1];

    float sx = 0.f, sy = 0.f;
    int i = start + sub;
    for (; i + 12 < end; i += 16) {       // 4 rows x unroll 4 in flight
        uint32 u0 = h[(size_t)i * 64 + c];
        uint32 u1 = h[(size_t)(i + 4) * 64 + c];
        uint32 u2 = h[(size_t)(i + 8) * 64 + c];
        uint32 u3 = h[(size_t)(i + 12) * 64 + c];
        float2 v0 = h2f2(u0), v1 = h2f2(u1), v2 = h2f2(u2), v3 = h2f2(u3);
        sx += v0.x + v1.x + v2.x + v3.x;
        sy += v0.y + v1.y + v2.y + v3.y;
    }
    for (; i < end; i += 4) {
        float2 v = h2f2(h[(size_t)i * 64 + c]);
        sx += v.x; sy += v.y;
    }
    *(float2*)&red[sub][2 * c] = make_float2(sx, sy);
    __syncthreads();

    if (t < 64) {
        float2 r0 = *(float2*)&red[0][2 * t];
        float2 r1 = *(float2*)&red[1][2 * t];
        float2 r2 = *(float2*)&red[2][2 * t];
        float2 r3 = *(float2*)&red[3][2 * t];
        float inv = 1.0f / fmaxf((float)(end - start), 1.0f);
        pp[2 * t]     = (r0.x + r1.x + r2.x + r3.x) * inv;
        pp[2 * t + 1] = (r0.y + r1.y + r2.y + r3.y) * inv;
        // same wave writes then reads pp: lgkmcnt ordering suffices
        float z = fc1b[t];
#pragma unroll 8
        for (int k = 0; k < HID; ++k) z += pp[k] * fc1w[k * 64 + t];
        z = fmaxf(z, 0.f);
        float v = z * fc2w[t];
#pragma unroll
        for (int off = 32; off > 0; off >>= 1) v += __shfl_down(v, off);
        if (t == 0) out[g] = v + fc2b[0];
    }
}

// ---------------------------------------------------------------------------
extern "C" void kernel_launch(void* const* d_in, const int* in_sizes, int n_in,
                              void* d_out, int out_size, void* d_ws, size_t ws_size,
                              hipStream_t stream) {
    const float* x     = (const float*)d_in[0];
    const int*   ei    = (const int*)d_in[1];
    const int*   batch = (const int*)d_in[2];
    const float* W1    = (const float*)d_in[3];
    const float* b1    = (const float*)d_in[4];
    const float* W2    = (const float*)d_in[5];
    const float* b2    = (const float*)d_in[6];
    const float* W3    = (const float*)d_in[7];
    const float* b3    = (const float*)d_in[8];
    const float* fc1w  = (const float*)d_in[9];
    const float* fc1b  = (const float*)d_in[10];
    const float* fc2w  = (const float*)d_in[11];
    const float* fc2b  = (const float*)d_in[12];
    float* out = (float*)d_out;

    const int N = in_sizes[0] / 6;   // 50000
    const int E = in_sizes[1] / 2;   // 600000
    const int* src = ei;
    const int* dst = ei + E;

    char* ws = (char*)d_ws;
    char* p = ws;
    uint32* S1   = (uint32*)p;   p += (size_t)(N + 1) * 256;      // dis*h1 fp16 plane (+pad row)
    uint32* S2   = (uint32*)p;   p += (size_t)(N + 1) * 256;      // dis*h2 fp16 plane (+pad row)
    uint32* B1h  = (uint32*)p;   p += (size_t)N * 256;            // fp16 final acts (h3)
    float4* xp4  = (float4*)p;   p += (size_t)N * 32;             // dis-scaled x rows
    ushort* WT   = (ushort*)p;   p += 2 * 32768;                  // packed W2,W3 (fp16)
    float* dis     = (float*)p;  p += (size_t)N * 4;
    int*   fill    = (int*)p;    p += (size_t)N * 4;
    int*   csr     = (int*)p;    p += (size_t)N * CAP * 4;        // capacity CSR
    int*   gstart  = (int*)p;    p += (NGRAPH + 1) * 4;           // pool segment bounds

    const int B = 256;
    const int EB = (E + B - 1) / B;

    // ---- setup + capacity-CSR build (no count pass, no scan) ----
    setup<<<(N + B - 1) / B, B, 0, stream>>>(fill, S1, S2, batch, gstart, N);
    csr_fill_pack<<<EB + 128, B, 0, stream>>>(src, dst, fill, csr, E, EB, W2, W3, WT);
    finalize<<<(N + B - 1) / B, B, 0, stream>>>(fill, dis, x, xp4, N);

    int nodeWaveBlocks = (int)(((size_t)N * 64 + B - 1) / B);
    int fusedBlocks = (N + NPB - 1) / NPB;

    // ---- layer 1 (fused aggregate + GEMM + bias + relu + dis-scale) ----
    layer1_fused<<<nodeWaveBlocks, B, 0, stream>>>(xp4, fill, csr, dis, W1, b1, S1, N);

    // ---- layer 2: fused (A*S1) then @W2 (+b2, relu, *dis) -> S2 ----
    layer_agg_gemm<8><<<fusedBlocks, B, 0, stream>>>(S1, fill, csr, dis, WT, b2, S2, N, 1);

    // ---- layer 3: fused (A*S2) then @W3 (+b3, relu) -> B1h (unscaled) ----
    layer_agg_gemm<8><<<fusedBlocks, B, 0, stream>>>(S2, fill, csr, dis, WT + 16384, b3, B1h, N, 0);

    // ---- fused pool + head (one block per graph, no atomics, no search) ----
    pool_head<<<NGRAPH, B, 0, stream>>>(B1h, gstart, fc1w, fc1b, fc2w, fc2b, out, N);
}

// Round 10
// 231.515 us; speedup vs baseline: 1.1517x; 1.1517x over previous
//
#include <hip/hip_runtime.h>
#include <hip/hip_fp16.h>

#define HID 128
#define NGRAPH 64
#define CAP 64        // fixed CSR capacity per row (Poisson lambda=12 -> safe)
#define NPB 16        // nodes per block (4 waves x 4 nodes) -> 3125 blocks supply

typedef unsigned int uint32;
typedef unsigned short ushort;
using short8 = __attribute__((ext_vector_type(8))) short;
using f32x4  = __attribute__((ext_vector_type(4))) float;

// fp16 pack/unpack helpers (RNE via v_cvt)
__device__ __forceinline__ float2 h2f2(uint32 u) {
    __half2 h = *(__half2*)&u;
    return __half22float2(h);
}
__device__ __forceinline__ uint32 f2h2(float a, float b) {
    __half2 h;
    h.x = __float2half(a);
    h.y = __float2half(b);
    return *(uint32*)&h;
}

// unpack one fp16x8 row chunk and accumulate into 8 fp32 lane-cols
__device__ __forceinline__ void accum4(float* acc, uint4 v) {
    float2 e0 = h2f2(v.x), e1 = h2f2(v.y), e2 = h2f2(v.z), e3 = h2f2(v.w);
    acc[0] += e0.x; acc[1] += e0.y; acc[2] += e1.x; acc[3] += e1.y;
    acc[4] += e2.x; acc[5] += e2.y; acc[6] += e3.x; acc[7] += e3.y;
}

// ---------------------------------------------------------------------------
// setup: fill=0, zero fp16 pad row (row n) of BOTH gather planes (S1, S2),
// and build gstart[0..NGRAPH] segment-boundary table from sorted batch.
// ---------------------------------------------------------------------------
__global__ void setup(int* __restrict__ fill, uint32* __restrict__ s1,
                      uint32* __restrict__ s2, const int* __restrict__ batch,
                      int* __restrict__ gstart, int n) {
    int i = blockIdx.x * blockDim.x + threadIdx.x;
    if (i < n) fill[i] = 0;
    if (i < 64) {
        s1[(size_t)n * 64 + i] = 0u;     // zero pad row of layer-1 plane
        s2[(size_t)n * 64 + i] = 0u;     // zero pad row of layer-2 plane
    }
    if (i < n) {
        int b0 = batch[i];
        if (i == 0) {
            for (int g = 0; g <= b0; ++g) gstart[g] = 0;   // leading (possibly empty)
        }
        if (i + 1 < n) {
            int b1 = batch[i + 1];
            for (int g = b0 + 1; g <= b1; ++g) gstart[g] = i + 1;
        } else {
            for (int g = b0 + 1; g <= NGRAPH; ++g) gstart[g] = n;  // trailing
        }
    }
}

// ---------------------------------------------------------------------------
// capacity-CSR fill + weight pack fused (single atomic pass, no scan).
// blocks [0,EB): pos = fill[dst]++ ; csr[dst*CAP+pos] = src.
// blocks [EB,EB+128): pack W2,W3 -> transposed single-plane fp16 wt[sel][n][k].
// NOTE: int (not ushort) CSR deliberately — the ushort variant core-dumped
// on HW in a previous round.
// ---------------------------------------------------------------------------
__global__ void csr_fill_pack(const int* __restrict__ src, const int* __restrict__ dst,
                              int* __restrict__ fill, int* __restrict__ csr,
                              int E, int EB,
                              const float* __restrict__ W2, const float* __restrict__ W3,
                              ushort* __restrict__ wt) {
    int b = blockIdx.x;
    if (b < EB) {
        int e = b * blockDim.x + threadIdx.x;
        if (e >= E) return;
        int d = dst[e];
        int pos = atomicAdd(&fill[d], 1);
        if (pos < CAP) csr[(size_t)d * CAP + pos] = src[e];
    } else {
        int t = (b - EB) * blockDim.x + threadIdx.x;   // 0..32767
        int sel = t >> 14;                             // 0: W2, 1: W3
        int idx = t & 16383;
        int nn = idx >> 7, kk = idx & 127;
        const float* W = sel ? W3 : W2;
        wt[sel * 16384 + idx] = __half_as_ushort(__float2half(W[kk * HID + nn]));
    }
}

// ---------------------------------------------------------------------------
// finalize: dis = 1/sqrt(deg) with deg = fill+1 (self-loop); pack
// xp[i] = dis[i] * x[i,:] into 32 B rows (vector-gatherable by layer 1).
// ---------------------------------------------------------------------------
__global__ void finalize(const int* __restrict__ fill, float* __restrict__ dis,
                         const float* __restrict__ x, float4* __restrict__ xp4, int n) {
    int i = blockIdx.x * blockDim.x + threadIdx.x;
    if (i >= n) return;
    int d = fill[i] + 1;
    float di = (float)(1.0 / sqrt((double)d));
    dis[i] = di;
    const float* xi = x + (size_t)i * 6;
    xp4[(size_t)i * 2]     = make_float4(di * xi[0], di * xi[1], di * xi[2], di * xi[3]);
    xp4[(size_t)i * 2 + 1] = make_float4(di * xi[4], di * xi[5], 0.f, 0.f);
}

// ---------------------------------------------------------------------------
// fused layer 1: one wave per node; m <= 64 so each lane gathers its own
// edge's xp row directly, 6 butterfly reductions, then each lane emits
// 2 fp16 output cols.  Stores S1 = dis * relu(xa@W1+b1).
// ---------------------------------------------------------------------------
__global__ __launch_bounds__(256) void layer1_fused(
    const float4* __restrict__ xp4, const int* __restrict__ fill,
    const int* __restrict__ csr, const float* __restrict__ dis,
    const float* __restrict__ W1, const float* __restrict__ b1,
    uint32* __restrict__ S1, int n) {
    int t = blockIdx.x * blockDim.x + threadIdx.x;
    int i = t >> 6, lane = t & 63;
    if (i >= n) return;
    int m = fill[i]; if (m > CAP) m = CAP;
    float a0 = 0.f, a1 = 0.f, a2 = 0.f, a3 = 0.f, a4 = 0.f, a5 = 0.f;
    if (lane < m) {
        int s = csr[(size_t)i * CAP + lane];
        float4 p0 = xp4[(size_t)s * 2];
        float4 p1 = xp4[(size_t)s * 2 + 1];
        a0 = p0.x; a1 = p0.y; a2 = p0.z;
        a3 = p0.w; a4 = p1.x; a5 = p1.y;
    }
#pragma unroll
    for (int off = 32; off > 0; off >>= 1) {
        a0 += __shfl_xor(a0, off); a1 += __shfl_xor(a1, off);
        a2 += __shfl_xor(a2, off); a3 += __shfl_xor(a3, off);
        a4 += __shfl_xor(a4, off); a5 += __shfl_xor(a5, off);
    }
    float di = dis[i];
    float4 s0 = xp4[(size_t)i * 2];
    float4 s1 = xp4[(size_t)i * 2 + 1];
    float xa[6];
    xa[0] = di * (s0.x + a0); xa[1] = di * (s0.y + a1);
    xa[2] = di * (s0.z + a2); xa[3] = di * (s0.w + a3);
    xa[4] = di * (s1.x + a4); xa[5] = di * (s1.y + a5);
    int c0 = lane * 2;
    float z0 = b1[c0], z1 = b1[c0 + 1];
#pragma unroll
    for (int k = 0; k < 6; ++k) {
        z0 += xa[k] * W1[k * HID + c0];
        z1 += xa[k] * W1[k * HID + c0 + 1];
    }
    // scale by dis so the plane is directly gatherable as S = dis*h
    S1[(size_t)i * 64 + lane] = f2h2(di * fmaxf(z0, 0.f), di * fmaxf(z1, 0.f));
}

// ---------------------------------------------------------------------------
// FUSED GCN layer (layers 2 & 3): aggregate-then-GEMM.
//   P_i    = dis_i * (sum_{j in N(i)} Sin_j + Sin_i)     (wave CSR gather)
//   Sout_i = [dis_i *] relu(P_i @ W + b)                 (MFMA, 16x16x32 f16)
//
// R10: NPB=16 supply (12.2 waves/SIMD) + spill-free register cap.
// R9's MINW=8 (64-VGPR cap) made the compiler emit VGPR=32 + scratch spills
// (WRITE_SIZE 12.5->77 MB) — but occupancy doubled to 60% and HBM rate
// doubled, proving supply-side TLP works once spills are gone.
// MINW=6 caps VGPR ~85 (6 resident waves/SIMD), enough for the proven
// 2-pair body (~70 live regs). Within-run A/B: layer 2 <6> vs layer 3 <5>.
// Mechanism check: VGPR 75-100, WRITE_SIZE ~12.5 MB, layer ~38-43 us.
// ---------------------------------------------------------------------------
template<int MINW>
__global__ __launch_bounds__(256, MINW) void layer_agg_gemm(
    const uint32* __restrict__ Sin, const int* __restrict__ fill,
    const int* __restrict__ csr, const float* __restrict__ dis,
    const ushort* __restrict__ WT, const float* __restrict__ bias,
    uint32* __restrict__ Sout, int n, int scaleOut) {
    __shared__ uint4 plds4[NPB * 17];           // 16 rows x 272 B = 4352 B
    const int wave = threadIdx.x >> 6;
    const int lane = threadIdx.x & 63;
    const int grp = lane >> 4;                  // edge-slot group 0..3
    const int q   = lane & 15;                  // uint4 col chunk (8 fp16)
    const int blk0 = blockIdx.x * NPB;
    const int base = blk0 + wave * 4;

    // ---- prologue: prefetch fill + csr index vectors for the 4 nodes ----
    int mt4[4];    // edge count incl. appended self-loop (<= 64)
    int idx4[4];   // this lane's edge slot for node j (pad -> zero row n)
#pragma unroll
    for (int j = 0; j < 4; ++j) {
        int i = base + j;
        int fv = (i < n) ? fill[i] : 0;
        int m = fv > CAP ? CAP : fv;
        idx4[j] = (lane < m) ? csr[(size_t)i * CAP + lane]
                             : ((lane == m && i < n && m < CAP) ? i : n);
        mt4[j] = m + (m < CAP ? 1 : 0);   // append self as slot m
    }

    // ---- phase A: paired gather-aggregate into LDS (2 pairs) ----
#pragma unroll
    for (int jp = 0; jp < 2; ++jp) {
        const int ja = jp * 2, jb = ja + 1;
        float acca[8] = {0.f, 0.f, 0.f, 0.f, 0.f, 0.f, 0.f, 0.f};
        float accb[8] = {0.f, 0.f, 0.f, 0.f, 0.f, 0.f, 0.f, 0.f};
        // first 16-edge round of BOTH nodes co-issued (8 uint4 in flight)
        {
            int sa1 = __shfl(idx4[ja], grp);
            int sa2 = __shfl(idx4[ja], 4 + grp);
            int sa3 = __shfl(idx4[ja], 8 + grp);
            int sa4 = __shfl(idx4[ja], 12 + grp);
            int sb1 = __shfl(idx4[jb], grp);
            int sb2 = __shfl(idx4[jb], 4 + grp);
            int sb3 = __shfl(idx4[jb], 8 + grp);
            int sb4 = __shfl(idx4[jb], 12 + grp);
            uint4 va1 = *(const uint4*)(Sin + (size_t)sa1 * 64 + q * 4);
            uint4 va2 = *(const uint4*)(Sin + (size_t)sa2 * 64 + q * 4);
            uint4 va3 = *(const uint4*)(Sin + (size_t)sa3 * 64 + q * 4);
            uint4 va4 = *(const uint4*)(Sin + (size_t)sa4 * 64 + q * 4);
            uint4 vb1 = *(const uint4*)(Sin + (size_t)sb1 * 64 + q * 4);
            uint4 vb2 = *(const uint4*)(Sin + (size_t)sb2 * 64 + q * 4);
            uint4 vb3 = *(const uint4*)(Sin + (size_t)sb3 * 64 + q * 4);
            uint4 vb4 = *(const uint4*)(Sin + (size_t)sb4 * 64 + q * 4);
            accum4(acca, va1); accum4(acca, va2);
            accum4(acca, va3); accum4(acca, va4);
            accum4(accb, vb1); accum4(accb, vb2);
            accum4(accb, vb3); accum4(accb, vb4);
        }
        // remainder rounds (m >= 16), serial per node
        for (int k = 16; k < mt4[ja]; k += 16) {
            int s1 = __shfl(idx4[ja], k + grp);
            int s2 = __shfl(idx4[ja], k + 4 + grp);
            int s3 = __shfl(idx4[ja], k + 8 + grp);
            int s4 = __shfl(idx4[ja], k + 12 + grp);
            uint4 v1 = *(const uint4*)(Sin + (size_t)s1 * 64 + q * 4);
            uint4 v2 = *(const uint4*)(Sin + (size_t)s2 * 64 + q * 4);
            uint4 v3 = *(const uint4*)(Sin + (size_t)s3 * 64 + q * 4);
            uint4 v4 = *(const uint4*)(Sin + (size_t)s4 * 64 + q * 4);
            accum4(acca, v1); accum4(acca, v2);
            accum4(acca, v3); accum4(acca, v4);
        }
        for (int k = 16; k < mt4[jb]; k += 16) {
            int s1 = __shfl(idx4[jb], k + grp);
            int s2 = __shfl(idx4[jb], k + 4 + grp);
            int s3 = __shfl(idx4[jb], k + 8 + grp);
            int s4 = __shfl(idx4[jb], k + 12 + grp);
            uint4 v1 = *(const uint4*)(Sin + (size_t)s1 * 64 + q * 4);
            uint4 v2 = *(const uint4*)(Sin + (size_t)s2 * 64 + q * 4);
            uint4 v3 = *(const uint4*)(Sin + (size_t)s3 * 64 + q * 4);
            uint4 v4 = *(const uint4*)(Sin + (size_t)s4 * 64 + q * 4);
            accum4(accb, v1); accum4(accb, v2);
            accum4(accb, v3); accum4(accb, v4);
        }
        // cross-group butterfly reduce (4 groups -> full row sums)
#pragma unroll
        for (int r = 0; r < 8; ++r) {
            acca[r] += __shfl_xor(acca[r], 16);
            acca[r] += __shfl_xor(acca[r], 32);
            accb[r] += __shfl_xor(accb[r], 16);
            accb[r] += __shfl_xor(accb[r], 32);
        }
        if (grp == 0) {
            int ia = base + ja, ib = base + jb;
            float da = (ia < n) ? dis[ia] : 0.f;
            float db = (ib < n) ? dis[ib] : 0.f;
            plds4[(wave * 4 + ja) * 17 + q] =
                make_uint4(f2h2(da * acca[0], da * acca[1]),
                           f2h2(da * acca[2], da * acca[3]),
                           f2h2(da * acca[4], da * acca[5]),
                           f2h2(da * acca[6], da * acca[7]));
            plds4[(wave * 4 + jb) * 17 + q] =
                make_uint4(f2h2(db * accb[0], db * accb[1]),
                           f2h2(db * accb[2], db * accb[3]),
                           f2h2(db * accb[4], db * accb[5]),
                           f2h2(db * accb[6], db * accb[7]));
        }
    }
    __syncthreads();

    // ---- phase B: 16x128 GEMM out = [dis*] relu(P @ W + b) ----
    // wave w owns cols [w*32, w*32+32); 16 rows; 8 MFMA per wave.
    const int l16 = lane & 15, quad = lane >> 4;
    f32x4 acc2[2] = {};
#pragma unroll
    for (int kc = 0; kc < 4; ++kc) {
        int ko = kc * 32 + quad * 8;
        short8 a0 = *(const short8*)&plds4[(size_t)l16 * 17 + kc * 4 + quad];
#pragma unroll
        for (int ct = 0; ct < 2; ++ct) {
            short8 wh = *(const short8*)(WT + (size_t)(wave * 32 + ct * 16 + l16) * HID + ko);
            acc2[ct] = __builtin_amdgcn_mfma_f32_16x16x32_f16(wh, a0, acc2[ct], 0, 0, 0);
        }
    }
    ushort* so = (ushort*)Sout;
    int node = blk0 + l16;
    if (node < n) {
        float sc = scaleOut ? dis[node] : 1.f;
#pragma unroll
        for (int ct = 0; ct < 2; ++ct) {
            int cb = wave * 32 + ct * 16 + quad * 4;
            float4 bv = *(const float4*)(bias + cb);
            float o0 = fmaxf(acc2[ct][0] + bv.x, 0.f) * sc;
            float o1 = fmaxf(acc2[ct][1] + bv.y, 0.f) * sc;
            float o2 = fmaxf(acc2[ct][2] + bv.z, 0.f) * sc;
            float o3 = fmaxf(acc2[ct][3] + bv.w, 0.f) * sc;
            *(uint2*)(so + (size_t)node * HID + cb) = make_uint2(f2h2(o0, o1), f2h2(o2, o3));
        }
    }
}

// ---------------------------------------------------------------------------
// FUSED pool + head: one block per graph; segment bounds from precomputed
// gstart table. 4 waves stream rows, LDS reduce, wave 0 runs the MLP head.
// ---------------------------------------------------------------------------
__global__ __launch_bounds__(256) void pool_head(
    const uint32* __restrict__ h, const int* __restrict__ gstart,
    const float* __restrict__ fc1w, const float* __restrict__ fc1b,
    const float* __restrict__ fc2w, const float* __restrict__ fc2b,
    float* __restrict__ out, int n) {
    __shared__ float red[4][128];
    __shared__ float pp[128];
    const int g = blockIdx.x;
    const int t = threadIdx.x;
    const int sub = t >> 6, c = t & 63;

    const int start = gstart[g], end = gstart[g + 1];

    float sx = 0.f, sy = 0.f;
    int i = start + sub;
    for (; i + 12 < end; i += 16) {       // 4 rows x unroll 4 in flight
        uint32 u0 = h[(size_t)i * 64 + c];
        uint32 u1 = h[(size_t)(i + 4) * 64 + c];
        uint32 u2 = h[(size_t)(i + 8) * 64 + c];
        uint32 u3 = h[(size_t)(i + 12) * 64 + c];
        float2 v0 = h2f2(u0), v1 = h2f2(u1), v2 = h2f2(u2), v3 = h2f2(u3);
        sx += v0.x + v1.x + v2.x + v3.x;
        sy += v0.y + v1.y + v2.y + v3.y;
    }
    for (; i < end; i += 4) {
        float2 v = h2f2(h[(size_t)i * 64 + c]);
        sx += v.x; sy += v.y;
    }
    *(float2*)&red[sub][2 * c] = make_float2(sx, sy);
    __syncthreads();

    if (t < 64) {
        float2 r0 = *(float2*)&red[0][2 * t];
        float2 r1 = *(float2*)&red[1][2 * t];
        float2 r2 = *(float2*)&red[2][2 * t];
        float2 r3 = *(float2*)&red[3][2 * t];
        float inv = 1.0f / fmaxf((float)(end - start), 1.0f);
        pp[2 * t]     = (r0.x + r1.x + r2.x + r3.x) * inv;
        pp[2 * t + 1] = (r0.y + r1.y + r2.y + r3.y) * inv;
        // same wave writes then reads pp: lgkmcnt ordering suffices
        float z = fc1b[t];
#pragma unroll 8
        for (int k = 0; k < HID; ++k) z += pp[k] * fc1w[k * 64 + t];
        z = fmaxf(z, 0.f);
        float v = z * fc2w[t];
#pragma unroll
        for (int off = 32; off > 0; off >>= 1) v += __shfl_down(v, off);
        if (t == 0) out[g] = v + fc2b[0];
    }
}

// ---------------------------------------------------------------------------
extern "C" void kernel_launch(void* const* d_in, const int* in_sizes, int n_in,
                              void* d_out, int out_size, void* d_ws, size_t ws_size,
                              hipStream_t stream) {
    const float* x     = (const float*)d_in[0];
    const int*   ei    = (const int*)d_in[1];
    const int*   batch = (const int*)d_in[2];
    const float* W1    = (const float*)d_in[3];
    const float* b1    = (const float*)d_in[4];
    const float* W2    = (const float*)d_in[5];
    const float* b2    = (const float*)d_in[6];
    const float* W3    = (const float*)d_in[7];
    const float* b3    = (const float*)d_in[8];
    const float* fc1w  = (const float*)d_in[9];
    const float* fc1b  = (const float*)d_in[10];
    const float* fc2w  = (const float*)d_in[11];
    const float* fc2b  = (const float*)d_in[12];
    float* out = (float*)d_out;

    const int N = in_sizes[0] / 6;   // 50000
    const int E = in_sizes[1] / 2;   // 600000
    const int* src = ei;
    const int* dst = ei + E;

    char* ws = (char*)d_ws;
    char* p = ws;
    uint32* S1   = (uint32*)p;   p += (size_t)(N + 1) * 256;      // dis*h1 fp16 plane (+pad row)
    uint32* S2   = (uint32*)p;   p += (size_t)(N + 1) * 256;      // dis*h2 fp16 plane (+pad row)
    uint32* B1h  = (uint32*)p;   p += (size_t)N * 256;            // fp16 final acts (h3)
    float4* xp4  = (float4*)p;   p += (size_t)N * 32;             // dis-scaled x rows
    ushort* WT   = (ushort*)p;   p += 2 * 32768;                  // packed W2,W3 (fp16)
    float* dis     = (float*)p;  p += (size_t)N * 4;
    int*   fill    = (int*)p;    p += (size_t)N * 4;
    int*   csr     = (int*)p;    p += (size_t)N * CAP * 4;        // capacity CSR
    int*   gstart  = (int*)p;    p += (NGRAPH + 1) * 4;           // pool segment bounds

    const int B = 256;
    const int EB = (E + B - 1) / B;

    // ---- setup + capacity-CSR build (no count pass, no scan) ----
    setup<<<(N + B - 1) / B, B, 0, stream>>>(fill, S1, S2, batch, gstart, N);
    csr_fill_pack<<<EB + 128, B, 0, stream>>>(src, dst, fill, csr, E, EB, W2, W3, WT);
    finalize<<<(N + B - 1) / B, B, 0, stream>>>(fill, dis, x, xp4, N);

    int nodeWaveBlocks = (int)(((size_t)N * 64 + B - 1) / B);
    int fusedBlocks = (N + NPB - 1) / NPB;

    // ---- layer 1 (fused aggregate + GEMM + bias + relu + dis-scale) ----
    layer1_fused<<<nodeWaveBlocks, B, 0, stream>>>(xp4, fill, csr, dis, W1, b1, S1, N);

    // ---- layer 2: fused (A*S1) then @W2 (+b2, relu, *dis) -> S2.  MINW=6 (A) ----
    layer_agg_gemm<6><<<fusedBlocks, B, 0, stream>>>(S1, fill, csr, dis, WT, b2, S2, N, 1);

    // ---- layer 3: fused (A*S2) then @W3 (+b3, relu) -> B1h.  MINW=5 (B) ----
    layer_agg_gemm<5><<<fusedBlocks, B, 0, stream>>>(S2, fill, csr, dis, WT + 16384, b3, B1h, N, 0);

    // ---- fused pool + head (one block per graph, no atomics, no search) ----
    pool_head<<<NGRAPH, B, 0, stream>>>(B1h, gstart, fc1w, fc1b, fc2w, fc2b, out, N);
}